// Round 7
// baseline (244.982 us; speedup 1.0000x reference)
//
#include <hip/hip_runtime.h>
#include <hip/hip_bf16.h>
#include <cstdint>

#define B_SZ   512
#define NLAT   64
#define H_SZ   32
#define G_OI_N 5000
#define K_SZ   64

// ---------------- Kernel A: h = BN(relu(latent @ W1 + b1)) -> fp32 [512][32]
__global__ __launch_bounds__(256) void mlp_kernel(
    const float* __restrict__ latent, const float* __restrict__ W1,
    const float* __restrict__ b1, const float* __restrict__ gamma,
    const float* __restrict__ beta, const float* __restrict__ mean,
    const float* __restrict__ var, float* __restrict__ hout)
{
    int idx = blockIdx.x * 256 + threadIdx.x;   // 0..16383 = b*32 + j
    int b = idx >> 5;
    int j = idx & 31;
    float acc = 0.f;
    const float4* lp = reinterpret_cast<const float4*>(latent + b * NLAT);
#pragma unroll
    for (int q = 0; q < NLAT / 4; ++q) {
        float4 lv = lp[q];
        acc = fmaf(lv.x, W1[(4 * q + 0) * H_SZ + j], acc);
        acc = fmaf(lv.y, W1[(4 * q + 1) * H_SZ + j], acc);
        acc = fmaf(lv.z, W1[(4 * q + 2) * H_SZ + j], acc);
        acc = fmaf(lv.w, W1[(4 * q + 3) * H_SZ + j], acc);
    }
    acc += b1[j];
    acc = fmaxf(acc, 0.f);
    acc = gamma[j] * (acc - mean[j]) * rsqrtf(var[j] + 1e-5f) + beta[j];
    hout[idx] = acc;
}

// ---------------- Kernel B: logit[b,g,k] = sum_h h[b,h] * lw[genes[g],h,k]
// Block = 4 genes (one per wave) x shared 128-row b-slice, h staged in LDS.
// h-reads move to the LDS pipe (broadcast ds_read_b128, 0 conflicts), leaving
// the VMEM pipe for the streaming nontemporal stores. wreg stays in VGPRs.
__global__ __launch_bounds__(256) void logit_kernel(
    const float* __restrict__ hbuf, const int* __restrict__ genes,
    const float* __restrict__ lw, float* __restrict__ out)
{
    __shared__ float hs[128 * H_SZ];           // 16 KB
    const int slice = blockIdx.x & 3;          // b-slice: 128 rows
    const int gq    = blockIdx.x >> 2;         // gene quad: 0..1249
    const int tid   = threadIdx.x;
    const int lane  = tid & 63;                // k
    const int w     = tid >> 6;                // wave -> gene within quad

    // stage h slice: 128 rows x 32 floats = 1024 float4 (256 threads x 4)
    {
        const float4* src = reinterpret_cast<const float4*>(hbuf + slice * 128 * H_SZ);
        float4* dst = reinterpret_cast<float4*>(hs);
#pragma unroll
        for (int p = 0; p < 4; ++p)
            dst[p * 256 + tid] = src[p * 256 + tid];
    }

    const int g = gq * 4 + w;                  // < 5000 always (1250*4)
    const size_t gene = (size_t)genes[g];
    const float* wp = lw + gene * (size_t)(H_SZ * K_SZ) + lane;
    float wreg[H_SZ];
#pragma unroll
    for (int hh = 0; hh < H_SZ; ++hh) wreg[hh] = wp[hh * K_SZ];

    __syncthreads();

    float* outp = out + (size_t)g * K_SZ + lane;
    const size_t brow = (size_t)(G_OI_N * K_SZ);
    const int b0 = slice * 128;
#pragma unroll 2
    for (int bb = 0; bb < 128; ++bb) {
        const float4* hp = reinterpret_cast<const float4*>(hs + bb * H_SZ);
        float a0 = 0.f, a1 = 0.f, a2 = 0.f, a3 = 0.f;
#pragma unroll
        for (int q = 0; q < 8; ++q) {
            float4 hv = hp[q];
            a0 = fmaf(hv.x, wreg[4 * q + 0], a0);
            a1 = fmaf(hv.y, wreg[4 * q + 1], a1);
            a2 = fmaf(hv.z, wreg[4 * q + 2], a2);
            a3 = fmaf(hv.w, wreg[4 * q + 3], a3);
        }
        __builtin_nontemporal_store((a0 + a1) + (a2 + a3),
                                    outp + (size_t)(b0 + bb) * brow);
    }
}

// ---------------- Kernel C: rho[b,g] = sum_h h[b,h] * rw[genes[g],h]
__global__ __launch_bounds__(256) void rho_kernel(
    const float* __restrict__ hbuf, const int* __restrict__ genes,
    const float* __restrict__ rw, float* __restrict__ out)
{
    const int gx = blockIdx.x % 20;
    const int bx = blockIdx.x / 20;
    const int g = gx * 256 + threadIdx.x;
    if (g >= G_OI_N) return;
    const size_t gene = (size_t)genes[g];

    float rreg[H_SZ];
    const float4* rp = reinterpret_cast<const float4*>(rw + gene * H_SZ);
#pragma unroll
    for (int q = 0; q < 8; ++q) {
        float4 rv = rp[q];
        rreg[4 * q + 0] = rv.x; rreg[4 * q + 1] = rv.y;
        rreg[4 * q + 2] = rv.z; rreg[4 * q + 3] = rv.w;
    }

    const int b0 = bx * 32;
    for (int b = b0; b < b0 + 32; ++b) {
        const float4* hp = reinterpret_cast<const float4*>(hbuf + b * H_SZ);
        float a0 = 0.f, a1 = 0.f, a2 = 0.f, a3 = 0.f;
#pragma unroll
        for (int q = 0; q < 8; ++q) {
            float4 hv = hp[q];
            a0 = fmaf(hv.x, rreg[4 * q + 0], a0);
            a1 = fmaf(hv.y, rreg[4 * q + 1], a1);
            a2 = fmaf(hv.z, rreg[4 * q + 2], a2);
            a3 = fmaf(hv.w, rreg[4 * q + 3], a3);
        }
        out[(size_t)b * G_OI_N + g] = (a0 + a1) + (a2 + a3);
    }
}

extern "C" void kernel_launch(void* const* d_in, const int* in_sizes, int n_in,
                              void* d_out, int out_size, void* d_ws, size_t ws_size,
                              hipStream_t stream)
{
    // Bind inputs by SIZE SIGNATURE (all sizes unique; robust to ordering).
    const float *latent = nullptr, *W1 = nullptr, *lw = nullptr, *rw = nullptr;
    const int* genes = nullptr;
    const float* small[5] = {nullptr, nullptr, nullptr, nullptr, nullptr};
    int nsmall = 0;
    for (int i = 0; i < n_in; ++i) {
        switch (in_sizes[i]) {
            case 32768:    latent = (const float*)d_in[i]; break;
            case 5000:
            case 10000:    genes  = (const int*)d_in[i];   break;
            case 2048:     W1     = (const float*)d_in[i]; break;
            case 40960000: lw     = (const float*)d_in[i]; break;
            case 640000:   rw     = (const float*)d_in[i]; break;
            case 32: if (nsmall < 5) small[nsmall++] = (const float*)d_in[i]; break;
            default: break;
        }
    }
    if (!latent || !genes || !W1 || !lw || !rw || nsmall < 5) return;
    const float* b1v   = small[0];
    const float* gamma = small[1];
    const float* beta  = small[2];
    const float* mean  = small[3];
    const float* var   = small[4];

    float* hbuf = (float*)d_ws;                               // 64 KB scratch
    float* logit_out = (float*)d_out;                         // [512,5000,64] fp32
    float* rho_out   = logit_out + (size_t)B_SZ * G_OI_N * K_SZ;  // [512,5000] fp32

    mlp_kernel<<<(B_SZ * H_SZ) / 256, 256, 0, stream>>>(latent, W1, b1v, gamma, beta,
                                                        mean, var, hbuf);
    logit_kernel<<<G_OI_N, 256, 0, stream>>>(hbuf, genes, lw, logit_out);
    rho_kernel<<<20 * 16, 256, 0, stream>>>(hbuf, genes, rw, rho_out);
}

// Round 8
// 220.415 us; speedup vs baseline: 1.1115x; 1.1115x over previous
//
#include <hip/hip_runtime.h>
#include <hip/hip_bf16.h>
#include <cstdint>

#define B_SZ   512
#define NLAT   64
#define H_SZ   32
#define G_OI_N 5000
#define K_SZ   64

typedef __attribute__((ext_vector_type(8))) short short8v;   // 8 x bf16
typedef __attribute__((ext_vector_type(4))) float float4v;

__device__ __forceinline__ unsigned short f2bf(float x) {
    union { float f; unsigned u; } v; v.f = x;
    unsigned r = v.u + 0x7fff + ((v.u >> 16) & 1);            // RTNE
    return (unsigned short)(r >> 16);
}

// ---------------- Kernel A: h = BN(relu(latent @ W1 + b1))
// writes fp32 h (for rho) and bf16 h (for logit MFMA A-operand)
__global__ __launch_bounds__(256) void mlp_kernel(
    const float* __restrict__ latent, const float* __restrict__ W1,
    const float* __restrict__ b1, const float* __restrict__ gamma,
    const float* __restrict__ beta, const float* __restrict__ mean,
    const float* __restrict__ var, float* __restrict__ hout,
    unsigned short* __restrict__ hbf)
{
    int idx = blockIdx.x * 256 + threadIdx.x;   // 0..16383 = b*32 + j
    int b = idx >> 5;
    int j = idx & 31;
    float acc = 0.f;
    const float4* lp = reinterpret_cast<const float4*>(latent + b * NLAT);
#pragma unroll
    for (int q = 0; q < NLAT / 4; ++q) {
        float4 lv = lp[q];
        acc = fmaf(lv.x, W1[(4 * q + 0) * H_SZ + j], acc);
        acc = fmaf(lv.y, W1[(4 * q + 1) * H_SZ + j], acc);
        acc = fmaf(lv.z, W1[(4 * q + 2) * H_SZ + j], acc);
        acc = fmaf(lv.w, W1[(4 * q + 3) * H_SZ + j], acc);
    }
    acc += b1[j];
    acc = fmaxf(acc, 0.f);
    acc = gamma[j] * (acc - mean[j]) * rsqrtf(var[j] + 1e-5f) + beta[j];
    hout[idx] = acc;
    hbf[idx]  = f2bf(acc);
}

// ---------------- Kernel B (MFMA): per gene C = h(512x32) @ lw[g](32x64)
// Block = 4 waves; wave u owns n-tile u (cols u*16..u*16+15 of the gene's 64).
// Wave preloads ALL 32 A-frags (h bf16) once, reuses across 4 genes.
// Layouts (m89/m91-verified): A[l&15,(l>>4)*8+j]; B[(l>>4)*8+j,l&15];
// D: col=l&15, row=(l>>4)*4+r.
__global__ __launch_bounds__(256) void logit_kernel(
    const unsigned short* __restrict__ hbf, const int* __restrict__ genes,
    const float* __restrict__ lw, float* __restrict__ out)
{
    const int lane  = threadIdx.x & 63;
    const int u     = threadIdx.x >> 6;      // n-tile 0..3
    const int row16 = lane & 15;
    const int kg    = lane >> 4;             // 0..3

    short8v afr[32];
#pragma unroll
    for (int t = 0; t < 32; ++t)
        afr[t] = *reinterpret_cast<const short8v*>(
                     hbf + (t * 16 + row16) * H_SZ + kg * 8);

    const int g0 = blockIdx.x * 4;
    for (int gi = 0; gi < 4; ++gi) {
        const int g = g0 + gi;
        const size_t gene = (size_t)genes[g];
        // B fragment: lw[gene, kg*8+j, u*16+row16], j=0..7 (stride 64 floats)
        const float* bp = lw + gene * (size_t)(H_SZ * K_SZ)
                             + (size_t)(kg * 8) * K_SZ + u * 16 + row16;
        short8v bfr;
#pragma unroll
        for (int j = 0; j < 8; ++j)
            bfr[j] = (short)f2bf(bp[(size_t)j * K_SZ]);

        float* og = out + (size_t)g * K_SZ + u * 16 + row16;
#pragma unroll
        for (int t = 0; t < 32; ++t) {
            float4v acc = {0.f, 0.f, 0.f, 0.f};
            acc = __builtin_amdgcn_mfma_f32_16x16x32_bf16(afr[t], bfr, acc, 0, 0, 0);
            const int brow = t * 16 + kg * 4;
#pragma unroll
            for (int r = 0; r < 4; ++r)
                og[(size_t)(brow + r) * (G_OI_N * K_SZ)] = acc[r];
        }
    }
}

// ---------------- Kernel C: rho[b,g] = sum_h h[b,h] * rw[genes[g],h]
__global__ __launch_bounds__(256) void rho_kernel(
    const float* __restrict__ hbuf, const int* __restrict__ genes,
    const float* __restrict__ rw, float* __restrict__ out)
{
    const int gx = blockIdx.x % 20;
    const int bx = blockIdx.x / 20;
    const int g = gx * 256 + threadIdx.x;
    if (g >= G_OI_N) return;
    const size_t gene = (size_t)genes[g];

    float rreg[H_SZ];
    const float4* rp = reinterpret_cast<const float4*>(rw + gene * H_SZ);
#pragma unroll
    for (int q = 0; q < 8; ++q) {
        float4 rv = rp[q];
        rreg[4 * q + 0] = rv.x; rreg[4 * q + 1] = rv.y;
        rreg[4 * q + 2] = rv.z; rreg[4 * q + 3] = rv.w;
    }

    const int b0 = bx * 32;
    for (int b = b0; b < b0 + 32; ++b) {
        const float4* hp = reinterpret_cast<const float4*>(hbuf + b * H_SZ);
        float a0 = 0.f, a1 = 0.f, a2 = 0.f, a3 = 0.f;
#pragma unroll
        for (int q = 0; q < 8; ++q) {
            float4 hv = hp[q];
            a0 = fmaf(hv.x, rreg[4 * q + 0], a0);
            a1 = fmaf(hv.y, rreg[4 * q + 1], a1);
            a2 = fmaf(hv.z, rreg[4 * q + 2], a2);
            a3 = fmaf(hv.w, rreg[4 * q + 3], a3);
        }
        out[(size_t)b * G_OI_N + g] = (a0 + a1) + (a2 + a3);
    }
}

extern "C" void kernel_launch(void* const* d_in, const int* in_sizes, int n_in,
                              void* d_out, int out_size, void* d_ws, size_t ws_size,
                              hipStream_t stream)
{
    // Bind inputs by SIZE SIGNATURE (all sizes unique; robust to ordering).
    const float *latent = nullptr, *W1 = nullptr, *lw = nullptr, *rw = nullptr;
    const int* genes = nullptr;
    const float* small[5] = {nullptr, nullptr, nullptr, nullptr, nullptr};
    int nsmall = 0;
    for (int i = 0; i < n_in; ++i) {
        switch (in_sizes[i]) {
            case 32768:    latent = (const float*)d_in[i]; break;
            case 5000:
            case 10000:    genes  = (const int*)d_in[i];   break;
            case 2048:     W1     = (const float*)d_in[i]; break;
            case 40960000: lw     = (const float*)d_in[i]; break;
            case 640000:   rw     = (const float*)d_in[i]; break;
            case 32: if (nsmall < 5) small[nsmall++] = (const float*)d_in[i]; break;
            default: break;
        }
    }
    if (!latent || !genes || !W1 || !lw || !rw || nsmall < 5) return;
    const float* b1v   = small[0];
    const float* gamma = small[1];
    const float* beta  = small[2];
    const float* mean  = small[3];
    const float* var   = small[4];

    float* hbuf = (float*)d_ws;                                    // 64 KB fp32 h
    unsigned short* hbf = (unsigned short*)((char*)d_ws + 65536);  // 32 KB bf16 h
    float* logit_out = (float*)d_out;                              // [512,5000,64]
    float* rho_out   = logit_out + (size_t)B_SZ * G_OI_N * K_SZ;   // [512,5000]

    mlp_kernel<<<(B_SZ * H_SZ) / 256, 256, 0, stream>>>(latent, W1, b1v, gamma, beta,
                                                        mean, var, hbuf, hbf);
    logit_kernel<<<G_OI_N / 4, 256, 0, stream>>>(hbf, genes, lw, logit_out);
    rho_kernel<<<20 * 16, 256, 0, stream>>>(hbuf, genes, rw, rho_out);
}